// Round 1
// baseline (1558.317 us; speedup 1.0000x reference)
//
#include <hip/hip_runtime.h>
#include <stdint.h>

typedef unsigned short u16;
typedef __attribute__((ext_vector_type(8))) short short8;
typedef __attribute__((ext_vector_type(4))) float floatx4;
typedef __attribute__((ext_vector_type(4))) unsigned short u16x4;

#define T_TOK 2048
#define NHEAD 32

__device__ __forceinline__ float bf2f(u16 u) { return __uint_as_float(((unsigned)u) << 16); }
__device__ __forceinline__ u16 f2bf(float f) {
    unsigned u = __float_as_uint(f);
    return (u16)((u + 0x7fffu + ((u >> 16) & 1u)) >> 16);
}

// ---------------------------------------------------------------------------
// Generic bf16 GEMM, C = A @ B^T.  A: M x K (lda), B: N x K (ldb, "BT" layout),
// C: M x N (ldc) as bf16 or f32.  Batched via grid.z with element strides.
// m97 structure: 128x128 tile, BK=32, global_load_lds width 16, 16x16x32 MFMA.
// Requires M%128==0, N%128==0, K%32==0 (guaranteed by caller / padding).
// ---------------------------------------------------------------------------
__global__ __launch_bounds__(256) void gemm_bt(
    const u16* __restrict__ A, const u16* __restrict__ B, void* __restrict__ Cp,
    int M, int N, int K, int lda, int ldb, int ldc,
    long sA, long sB, long sC, int c_bf16)
{
    __shared__ u16 As[128 * 32];
    __shared__ u16 Bs[128 * 32];
    const int z = blockIdx.z;
    A += (long)z * sA;
    B += (long)z * sB;
    const int tid  = threadIdx.x;
    const int wave = tid >> 6;
    const int lane = tid & 63;
    const long m0 = (long)blockIdx.y * 128;
    const long n0 = (long)blockIdx.x * 128;
    const int wm = (wave & 1) * 64;
    const int wn = (wave >> 1) * 64;
    const int lr = lane & 15;
    const int lk = (lane >> 4) * 8;

    const u16* Ag = A + (m0 + (tid >> 2)) * (long)lda + (tid & 3) * 8;
    const u16* Bg = B + (n0 + (tid >> 2)) * (long)ldb + (tid & 3) * 8;
    const long a64 = (long)64 * lda, b64 = (long)64 * ldb;

    floatx4 acc[4][4] = {};

    for (int k0 = 0; k0 < K; k0 += 32) {
        __syncthreads();
        __builtin_amdgcn_global_load_lds(
            (const __attribute__((address_space(1))) void*)(Ag + k0),
            (__attribute__((address_space(3))) void*)(As + wave * 512), 16, 0, 0);
        __builtin_amdgcn_global_load_lds(
            (const __attribute__((address_space(1))) void*)(Ag + k0 + a64),
            (__attribute__((address_space(3))) void*)(As + 2048 + wave * 512), 16, 0, 0);
        __builtin_amdgcn_global_load_lds(
            (const __attribute__((address_space(1))) void*)(Bg + k0),
            (__attribute__((address_space(3))) void*)(Bs + wave * 512), 16, 0, 0);
        __builtin_amdgcn_global_load_lds(
            (const __attribute__((address_space(1))) void*)(Bg + k0 + b64),
            (__attribute__((address_space(3))) void*)(Bs + 2048 + wave * 512), 16, 0, 0);
        __syncthreads();
        short8 af[4], bfr[4];
#pragma unroll
        for (int t = 0; t < 4; t++) {
            af[t]  = *(const short8*)&As[(wm + t * 16 + lr) * 32 + lk];
            bfr[t] = *(const short8*)&Bs[(wn + t * 16 + lr) * 32 + lk];
        }
#pragma unroll
        for (int mt = 0; mt < 4; mt++)
#pragma unroll
            for (int nt = 0; nt < 4; nt++)
                acc[mt][nt] = __builtin_amdgcn_mfma_f32_16x16x32_bf16(
                    af[mt], bfr[nt], acc[mt][nt], 0, 0, 0);
    }

    const int rbase = wm + (lane >> 4) * 4;
    if (c_bf16) {
        u16* C = (u16*)Cp + (long)z * sC;
#pragma unroll
        for (int mt = 0; mt < 4; mt++)
#pragma unroll
            for (int nt = 0; nt < 4; nt++)
#pragma unroll
                for (int r = 0; r < 4; r++) {
                    long row = m0 + rbase + mt * 16 + r;
                    long col = n0 + wn + nt * 16 + lr;
                    C[row * ldc + col] = f2bf(acc[mt][nt][r]);
                }
    } else {
        float* C = (float*)Cp + (long)z * sC;
#pragma unroll
        for (int mt = 0; mt < 4; mt++)
#pragma unroll
            for (int nt = 0; nt < 4; nt++)
#pragma unroll
                for (int r = 0; r < 4; r++) {
                    long row = m0 + rbase + mt * 16 + r;
                    long col = n0 + wn + nt * 16 + lr;
                    C[row * ldc + col] = acc[mt][nt][r];
                }
    }
}

// f32 -> bf16 elementwise cast (n multiple of 4)
__global__ __launch_bounds__(256) void cast_bf16_k(const float* __restrict__ src,
                                                   u16* __restrict__ dst, long n)
{
    long i = ((long)blockIdx.x * 256 + threadIdx.x) * 4;
    if (i + 3 < n) {
        float4 v = *(const float4*)(src + i);
        u16x4 o = { f2bf(v.x), f2bf(v.y), f2bf(v.z), f2bf(v.w) };
        *(u16x4*)(dst + i) = o;
    }
}

// src (R x C) f32 row-major -> dst (Cpad x R) bf16 (transposed); rows C..Cpad zero
__global__ void transpose_cast(const float* __restrict__ src, u16* __restrict__ dst,
                               int R, int C, int Cpad)
{
    __shared__ float tile[32][33];
    const int cb = blockIdx.x * 32, rb = blockIdx.y * 32;
    for (int i = threadIdx.y; i < 32; i += 8) {
        int r = rb + i, c = cb + threadIdx.x;
        tile[i][threadIdx.x] = (r < R && c < C) ? src[(long)r * C + c] : 0.0f;
    }
    __syncthreads();
    for (int i = threadIdx.y; i < 32; i += 8) {
        int c = cb + i, r = rb + threadIdx.x;
        if (c < Cpad && r < R) dst[(long)c * R + r] = f2bf(tile[threadIdx.x][i]);
    }
}

// w_uv (KVL=512, H=32, DV=128) f32 -> dst[h][d][r] bf16 (per-head BT layout)
__global__ __launch_bounds__(256) void permute_wuv(const float* __restrict__ src,
                                                   u16* __restrict__ dst)
{
    int idx = blockIdx.x * 256 + threadIdx.x;   // 2,097,152 total
    int r = idx & 511;
    int hd = idx >> 9;            // h*128 + d
    int d = hd & 127, h = hd >> 7;
    dst[idx] = f2bf(src[(long)r * 4096 + h * 128 + d]);
}

// RMSNorm rows (bf16 in/out, fp32 accumulate)
__global__ __launch_bounds__(256) void rmsnorm_rows(const u16* __restrict__ in,
                                                    const float* __restrict__ gamma,
                                                    u16* __restrict__ out, int n, float invn)
{
    const long base = (long)blockIdx.x * n;
    const int tid = threadIdx.x, wave = tid >> 6, lane = tid & 63;
    __shared__ float red[4];
    float ss = 0.f;
    for (int i = tid; i < n; i += 256) { float x = bf2f(in[base + i]); ss += x * x; }
    for (int o = 32; o > 0; o >>= 1) ss += __shfl_xor(ss, o);
    if (lane == 0) red[wave] = ss;
    __syncthreads();
    ss = red[0] + red[1] + red[2] + red[3];
    const float r = rsqrtf(ss * invn + 1e-6f);
    for (int i = tid; i < n; i += 256) {
        float x = bf2f(in[base + i]);
        out[base + i] = f2bf(x * r * gamma[i]);
    }
}

// kv_a post-process: rmsnorm first 512 cols -> Kp[:, :512] and compressed^T;
// rope on cols 512..576 -> Kp[:, 512:576].  in ld = 640 (padded), Kp ld = 576.
__global__ __launch_bounds__(256) void kv_post(const u16* __restrict__ kva,
                                               const float* __restrict__ gamma,
                                               const int* __restrict__ pos,
                                               u16* __restrict__ Kp, u16* __restrict__ cmpT)
{
    const int t = blockIdx.x;
    const long base = (long)t * 640;
    const int tid = threadIdx.x, wave = tid >> 6, lane = tid & 63;
    __shared__ float red[4];
    float ss = 0.f;
    for (int i = tid; i < 512; i += 256) { float x = bf2f(kva[base + i]); ss += x * x; }
    for (int o = 32; o > 0; o >>= 1) ss += __shfl_xor(ss, o);
    if (lane == 0) red[wave] = ss;
    __syncthreads();
    ss = red[0] + red[1] + red[2] + red[3];
    const float r = rsqrtf(ss * (1.0f / 512.0f) + 1e-6f);
    for (int i = tid; i < 512; i += 256) {
        float x = bf2f(kva[base + i]) * r * gamma[i];
        u16 u = f2bf(x);
        Kp[(long)t * 576 + i] = u;
        cmpT[(long)i * T_TOK + t] = u;
    }
    if (tid < 32) {
        int j = tid;
        float invf = powf(10000.0f, -(float)j / 32.0f);
        float ang = (float)pos[t] * invf;
        float sn, cs;
        sincosf(ang, &sn, &cs);
        float x1 = bf2f(kva[base + 512 + 2 * j]);
        float x2 = bf2f(kva[base + 512 + 2 * j + 1]);
        Kp[(long)t * 576 + 512 + 2 * j]     = f2bf(x1 * cs - x2 * sn);
        Kp[(long)t * 576 + 512 + 2 * j + 1] = f2bf(x1 * sn + x2 * cs);
    }
}

// rope on q_rope part of q (T,H,192) -> Qp[h][t][512..576]
__global__ __launch_bounds__(256) void rope_q(const u16* __restrict__ q,
                                              const int* __restrict__ pos,
                                              u16* __restrict__ Qp)
{
    int idx = blockIdx.x * 256 + threadIdx.x;    // T*H*32 = 2,097,152
    int j = idx & 31;
    int h = (idx >> 5) & 31;
    int t = idx >> 10;
    float invf = powf(10000.0f, -(float)j / 32.0f);
    float ang = (float)pos[t] * invf;
    float sn, cs;
    sincosf(ang, &sn, &cs);
    long qb = (long)t * 6144 + h * 192 + 128 + 2 * j;
    float x1 = bf2f(q[qb]), x2 = bf2f(q[qb + 1]);
    long ob = (long)h * T_TOK * 576 + (long)t * 576 + 512 + 2 * j;
    Qp[ob]     = f2bf(x1 * cs - x2 * sn);
    Qp[ob + 1] = f2bf(x1 * sn + x2 * cs);
}

// causal masked softmax, in-place on bf16 scores (z heads in grid.y)
__global__ __launch_bounds__(256) void softmax_causal(u16* __restrict__ buf, float scale)
{
    const int t = blockIdx.x;
    const long base = (long)blockIdx.y * T_TOK * T_TOK + (long)t * T_TOK;
    const int n = t + 1;
    const int tid = threadIdx.x, wave = tid >> 6, lane = tid & 63;
    __shared__ float red[8];
    float m = -3.0e38f;
    for (int i = tid; i < n; i += 256) m = fmaxf(m, scale * bf2f(buf[base + i]));
    for (int o = 32; o > 0; o >>= 1) m = fmaxf(m, __shfl_xor(m, o));
    if (lane == 0) red[wave] = m;
    __syncthreads();
    m = fmaxf(fmaxf(red[0], red[1]), fmaxf(red[2], red[3]));
    float s = 0.f;
    for (int i = tid; i < n; i += 256) s += expf(scale * bf2f(buf[base + i]) - m);
    for (int o = 32; o > 0; o >>= 1) s += __shfl_xor(s, o);
    if (lane == 0) red[4 + wave] = s;
    __syncthreads();
    s = red[4] + red[5] + red[6] + red[7];
    const float inv = 1.0f / s;
    for (int i = tid; i < T_TOK; i += 256) {
        float p = (i < n) ? expf(scale * bf2f(buf[base + i]) - m) * inv : 0.f;
        buf[base + i] = f2bf(p);
    }
}

extern "C" void kernel_launch(void* const* d_in, const int* in_sizes, int n_in,
                              void* d_out, int out_size, void* d_ws, size_t ws_size,
                              hipStream_t stream)
{
    const float* hidden = (const float*)d_in[0];
    const int* positions = (const int*)d_in[1];
    const float* w_qa  = (const float*)d_in[2];
    const float* qa_g  = (const float*)d_in[3];
    const float* w_qb  = (const float*)d_in[4];
    const float* w_kva = (const float*)d_in[5];
    const float* kva_g = (const float*)d_in[6];
    const float* w_uk  = (const float*)d_in[7];
    const float* w_uv  = (const float*)d_in[8];
    const float* w_o   = (const float*)d_in[9];

    char* ws = (char*)d_ws;
    // Region R (67,108,864 B): early-stage buffers, all dead before o_lat is
    // written during attention -> o_lat aliases the whole region.
    u16* o_lat   = (u16*)(ws + 0);
    u16* qc      = (u16*)(ws + 0);
    u16* q       = (u16*)(ws + 6291456);
    u16* hid_bf  = (u16*)(ws + 31457280);
    u16* wqa_t   = (u16*)(ws + 48234496);
    u16* qc_raw  = (u16*)(ws + 60817408);
    u16* wqb_t   = (u16*)(ws + 67108864);
    u16* wkva_t  = (u16*)(ws + 85983232);
    u16* wuk_b   = (u16*)(ws + 91226112);
    u16* wuv_t   = (u16*)(ws + 95420416);
    u16* wo_t    = (u16*)(ws + 99614720);
    u16* kva_raw = (u16*)(ws + 133169152);
    u16* Kp      = (u16*)(ws + 135790592);
    u16* cmpT    = (u16*)(ws + 138149888);
    u16* Qp      = (u16*)(ws + 140247040);   // 75,497,472 B; total ws use 215,744,512 B
    u16* o_v     = Qp;                        // alias: Qp dead after attention
    u16* scores  = (u16*)d_out;               // 4 heads * T*T bf16 == d_out bytes exactly

    // --- stage 0: casts / relayouts to bf16 (all B operands to N x K) -------
    cast_bf16_k<<<8192, 256, 0, stream>>>(hidden, hid_bf, 8388608);
    transpose_cast<<<dim3(48, 128),  dim3(32, 8), 0, stream>>>(w_qa,  wqa_t,  4096, 1536, 1536);
    transpose_cast<<<dim3(192, 48),  dim3(32, 8), 0, stream>>>(w_qb,  wqb_t,  1536, 6144, 6144);
    transpose_cast<<<dim3(20, 128),  dim3(32, 8), 0, stream>>>(w_kva, wkva_t, 4096, 576,  640);
    cast_bf16_k<<<2048, 256, 0, stream>>>(w_uk, wuk_b, 2097152);
    permute_wuv<<<8192, 256, 0, stream>>>(w_uv, wuv_t);
    transpose_cast<<<dim3(128, 128), dim3(32, 8), 0, stream>>>(w_o,   wo_t,   4096, 4096, 4096);

    // --- stage 1: LoRA-A projections + norms --------------------------------
    gemm_bt<<<dim3(12, 16, 1), 256, 0, stream>>>(hid_bf, wqa_t, qc_raw,
        2048, 1536, 4096, 4096, 4096, 1536, 0, 0, 0, 1);
    gemm_bt<<<dim3(5, 16, 1), 256, 0, stream>>>(hid_bf, wkva_t, kva_raw,
        2048, 640, 4096, 4096, 4096, 640, 0, 0, 0, 1);
    rmsnorm_rows<<<2048, 256, 0, stream>>>(qc_raw, qa_g, qc, 1536, 1.0f / 1536.0f);
    kv_post<<<2048, 256, 0, stream>>>(kva_raw, kva_g, positions, Kp, cmpT);

    // --- stage 2: q up-projection, rope, per-head absorb --------------------
    gemm_bt<<<dim3(48, 16, 1), 256, 0, stream>>>(qc, wqb_t, q,
        2048, 6144, 1536, 1536, 1536, 6144, 0, 0, 0, 1);
    rope_q<<<8192, 256, 0, stream>>>(q, positions, Qp);
    gemm_bt<<<dim3(4, 16, 32), 256, 0, stream>>>(q, wuk_b, Qp,
        2048, 512, 128, 6144, 4096, 576, 192, 128, (long)2048 * 576, 1);

    // --- stage 3: attention, 8 batches of 4 heads ---------------------------
    const float scale = 0.07216878364870323f;   // 1/sqrt(192)
    for (int hb = 0; hb < 8; hb++) {
        gemm_bt<<<dim3(16, 16, 4), 256, 0, stream>>>(
            Qp + (long)hb * 4 * 2048 * 576, Kp, scores,
            2048, 2048, 576, 576, 576, 2048, (long)2048 * 576, 0, (long)2048 * 2048, 1);
        softmax_causal<<<dim3(2048, 4), 256, 0, stream>>>(scores, scale);
        gemm_bt<<<dim3(4, 16, 4), 256, 0, stream>>>(
            scores, cmpT, o_lat + (long)hb * 4 * 2048 * 512,
            2048, 512, 2048, 2048, 2048, 512, (long)2048 * 2048, 0, (long)2048 * 512, 1);
    }

    // --- stage 4: o_v and output projection ---------------------------------
    gemm_bt<<<dim3(1, 16, 32), 256, 0, stream>>>(o_lat, wuv_t, o_v,
        2048, 128, 512, 512, 512, 4096, (long)2048 * 512, 65536, 128, 1);
    gemm_bt<<<dim3(32, 16, 1), 256, 0, stream>>>(o_v, wo_t, d_out,
        2048, 4096, 4096, 4096, 4096, 4096, 0, 0, 0, 0);
}